// Round 6
// baseline (630.924 us; speedup 1.0000x reference)
//
#include <hip/hip_runtime.h>
#include <hip/hip_cooperative_groups.h>

namespace cg = cooperative_groups;

#define N_NODES 100000
#define D 128

typedef unsigned short u16;
typedef short s16x8 __attribute__((ext_vector_type(8)));
typedef float f32x4 __attribute__((ext_vector_type(4)));
typedef unsigned u32x4 __attribute__((ext_vector_type(4)));

// ---------------- ws layout ----------------
// ints (4B):
//   deg    @ 0        (300000)   per-type in-degree [type*100000 + d]
//   offs   @ 300000   (100001)   unified entry-list exclusive scan (+sentinel)
//   cursor @ 400001   (300000)   per-(type,dest) segment cursors
//   flags  @ 700001   (128)      lookback-scan state: (sum<<2)|st
// int  ents @ byte 2804224  (1,600,000 x 4B = 6.4 MB)  src node index only
// u16  ATb  @ byte 9204224  (7 x 16384 = 229 KB)  transposed bf16 weights [slot][n][k]
// u16  xb   @ byte 9433600  (100000 x 128 = 25.6 MB) compact bf16 x
// u16  G    @ byte 35033600 (100000 x 6 x 128 = 153.6 MB) aggregated slots (nt streamed)
// total ~188.6 MB

#define ENTS_OFF 2804224L
#define AT_OFF   9204224L
#define XB_OFF   9433600L
#define G_OFF    35033600L

__device__ __forceinline__ u16 f2b(float f) {
    union { float f; unsigned u; } v; v.f = f;
    unsigned r = (v.u + 0x7FFFu + ((v.u >> 16) & 1u)) >> 16;
    return (u16)r;
}
__device__ __forceinline__ unsigned pk(float lo, float hi) {
    return (unsigned)f2b(lo) | ((unsigned)f2b(hi) << 16);
}
__device__ __forceinline__ float blo(unsigned w) { return __uint_as_float(w << 16); }
__device__ __forceinline__ float bhi(unsigned w) { return __uint_as_float(w & 0xFFFF0000u); }

// ---------------- K1 (cooperative): zero -> init/deg -> scan -> scatter ----------------
// Replaces 4 serialized launches with one kernel + 3 grid.sync()s.
// 1024 blocks x 256 thr (4 blocks/CU guaranteed co-resident; 1KB LDS, VGPR<=128).
// Phase bodies are the proven round-5 kernels, grid-strided.

__global__ __launch_bounds__(256, 4) void pre_all(
    const float* __restrict__ x,
    const float* __restrict__ A1, const float* __restrict__ A2,
    const float* __restrict__ A3, const float* __restrict__ Cw,
    const int* __restrict__ e1, const int* __restrict__ e2, const int* __restrict__ e3,
    int ne1, int ne2, int ne3,
    u16* __restrict__ ATb, u16* __restrict__ xb, int* __restrict__ deg,
    int* __restrict__ offs, int* __restrict__ cursor, int* __restrict__ flags,
    int* __restrict__ ents) {
    cg::grid_group grid = cg::this_grid();
    __shared__ int s[256];
    __shared__ int bprefix;
    const int b = blockIdx.x, t = threadIdx.x;
    const int nblk = gridDim.x;            // 1024
    const int net = ne1 + ne2 + ne3;

    // ---- phase A: zero deg + flags ----
    for (int i = b * 256 + t; i < 300000; i += nblk * 256) deg[i] = 0;
    if (b == 0 && t < 128) flags[t] = 0;
    grid.sync();

    // ---- phase B: ATb convert + x->xb + per-type in-degree (virtual blocks) ----
    const int nvb = 448 + 6250 + (net + 255) / 256;
    for (int vb = b; vb < nvb; vb += nblk) {
        if (vb < 448) {
            int m = vb >> 6;
            int idx = (vb & 63) * 256 + t;  // 0..16383
            int n = idx >> 7, kk = idx & 127;
            const float* src; int srow;
            if (m == 0)      { src = A1; srow = kk; }
            else if (m < 3)  { src = A2; srow = (m - 1) * 128 + kk; }
            else if (m < 6)  { src = A3; srow = (m - 3) * 128 + kk; }
            else             { src = Cw; srow = kk; }
            ATb[m * 16384 + n * 128 + kk] = f2b(src[(long)srow * 128 + n]);
        } else if (vb < 6698) {
            int f = (vb - 448) * 256 + t;          // 0..1,599,999 exact
            int node = f >> 4, j = f & 15;
            const f32x4* xr = (const f32x4*)(x + (long)node * 128 + j * 8);
            f32x4 v0 = __builtin_nontemporal_load(xr);
            f32x4 v1 = __builtin_nontemporal_load(xr + 1);
            u32x4 o;
            o.x = pk(v0.x, v0.y); o.y = pk(v0.z, v0.w);
            o.z = pk(v1.x, v1.y); o.w = pk(v1.z, v1.w);
            *(u32x4*)(xb + (long)node * 128 + j * 8) = o;
        } else {
            int g = (vb - 6698) * 256 + t;
            if (g < ne1) {
                atomicAdd(&deg[e1[ne1 + g]], 1);
            } else if (g < ne1 + ne2) {
                int e = g - ne1;
                atomicAdd(&deg[N_NODES + e2[ne2 * 2 + e * 2]], 1);
            } else if (g < net) {
                int e = g - ne1 - ne2;
                atomicAdd(&deg[2 * N_NODES + e3[ne3 * 3 + e * 3]], 1);
            }
        }
    }
    grid.sync();

    // ---- phase C: decoupled-lookback scan + cursor seeding (98 active blocks) ----
    const int n = N_NODES;
    const int nb = (n + 1023) / 1024;      // 98
    if (b < nb) {
        int base = b * 1024 + t * 4;
        int d1[4], d2[4], v[4], p[4];
#pragma unroll
        for (int r = 0; r < 4; r++) {
            int idx = base + r;
            if (idx < n) {
                d1[r] = deg[idx];
                d2[r] = deg[N_NODES + idx];
                int d3 = deg[2 * N_NODES + idx];
                v[r] = d1[r] + 2 * d2[r] + 3 * d3;
            } else { d1[r] = 0; d2[r] = 0; v[r] = 0; }
        }
        p[0] = 0; p[1] = v[0]; p[2] = v[0] + v[1]; p[3] = v[0] + v[1] + v[2];
        int tsum = p[3] + v[3];
        s[t] = tsum;
        for (int off = 1; off < 256; off <<= 1) {
            __syncthreads();
            int xx = (t >= off) ? s[t - off] : 0;
            __syncthreads();
            s[t] += xx;
        }
        __syncthreads();
        int total = s[255];
        if (t == 0) {
            int run = 0;
            if (b == 0) {
                atomicExch(&flags[0], (total << 2) | 2);
            } else {
                atomicExch(&flags[b], (total << 2) | 1);
                int j = b - 1;
                while (true) {
                    int f = atomicAdd(&flags[j], 0);
                    int st = f & 3;
                    if (st == 0) continue;
                    run += (f >> 2);
                    if (st == 2) break;
                    j--;
                }
                atomicExch(&flags[b], ((run + total) << 2) | 2);
            }
            bprefix = run;
            if (b == nb - 1) offs[n] = run + total;
        }
        __syncthreads();
        int texcl = s[t] - tsum + bprefix;
#pragma unroll
        for (int r = 0; r < 4; r++) {
            int idx = base + r;
            if (idx < n) {
                int val = texcl + p[r];
                offs[idx] = val;
                cursor[idx] = val;                                    // r1 segment
                cursor[N_NODES + idx] = val + d1[r];                  // r2 slot-1 seg
                cursor[2 * N_NODES + idx] = val + d1[r] + 2 * d2[r];  // r3 slot-3 seg
            }
        }
    }
    grid.sync();

    // ---- phase D: scatter src indices into slot-segmented entry list ----
    // dest range layout: [c1 slot0][c2 slot1][c2 slot2][c3 slot3][c3 slot4][c3 slot5]
    for (int g = b * 256 + t; g < net; g += nblk * 256) {
        if (g < ne1) {
            int dest = e1[ne1 + g];
            int pos = atomicAdd(&cursor[dest], 1);
            ents[pos] = e1[g];
        } else if (g < ne1 + ne2) {
            int e = g - ne1;
            int dest = e2[ne2 * 2 + e * 2];
            int c2 = deg[N_NODES + dest];
            int pos = atomicAdd(&cursor[N_NODES + dest], 1);
            ents[pos]      = e2[e * 2];
            ents[pos + c2] = e2[e * 2 + 1];
        } else {
            int e = g - ne1 - ne2;
            int dest = e3[ne3 * 3 + e * 3];
            int c3 = deg[2 * N_NODES + dest];
            int pos = atomicAdd(&cursor[2 * N_NODES + dest], 1);
            ents[pos]          = e3[e * 3];
            ents[pos + c3]     = e3[e * 3 + 1];
            ents[pos + 2 * c3] = e3[e * 3 + 2];
        }
    }
}

// ---------------- K2: aggregate — G[d][s] = (1/c_t) * sum xb[src] ----------------
// Unchanged from round 5 (proven 81 us; fetch at compulsory cross-XCD floor).

__global__ __launch_bounds__(256) void agg_all(
    const u16* __restrict__ xb, const int* __restrict__ ents,
    const int* __restrict__ offs, const int* __restrict__ deg,
    u16* __restrict__ G) {
    const int lane = threadIdx.x & 63;
    const int wv = __builtin_amdgcn_readfirstlane(threadIdx.x >> 6);
    int wid = blockIdx.x * 4 + wv;
    const int nw = gridDim.x * 4;
    const unsigned cb = (unsigned)lane * 4u;  // lane's byte offset within a 256B row
    const char* xbb = (const char*)xb;

    for (int d = wid; d < N_NODES; d += nw) {
        const int lo = offs[d];
        const int c1 = deg[d], c2 = deg[N_NODES + d], c3 = deg[2 * N_NODES + d];
        float a0l = 0, a0h = 0, a1l = 0, a1h = 0, a2l = 0, a2h = 0;
        float a3l = 0, a3h = 0, a4l = 0, a4h = 0, a5l = 0, a5h = 0;

        // ---- r1 stream: 8-deep unmasked batches + tail ----
        int p = 0;
        for (; p + 8 <= c1; p += 8) {
            unsigned w[8];
#pragma unroll
            for (int i = 0; i < 8; i++)
                w[i] = *(const unsigned*)(xbb + (((unsigned)ents[lo + p + i] << 8) + cb));
#pragma unroll
            for (int i = 0; i < 8; i++) { a0l += blo(w[i]); a0h += bhi(w[i]); }
        }
        for (; p < c1; p++) {
            unsigned w = *(const unsigned*)(xbb + (((unsigned)ents[lo + p] << 8) + cb));
            a0l += blo(w); a0h += bhi(w);
        }

        // ---- r2 stream: 4-deep x 2 slots ----
        const int o1 = lo + c1;
        p = 0;
        for (; p + 4 <= c2; p += 4) {
            unsigned wa[4], wb[4];
#pragma unroll
            for (int i = 0; i < 4; i++) {
                int e = o1 + p + i;
                wa[i] = *(const unsigned*)(xbb + (((unsigned)ents[e] << 8) + cb));
                wb[i] = *(const unsigned*)(xbb + (((unsigned)ents[e + c2] << 8) + cb));
            }
#pragma unroll
            for (int i = 0; i < 4; i++) {
                a1l += blo(wa[i]); a1h += bhi(wa[i]);
                a2l += blo(wb[i]); a2h += bhi(wb[i]);
            }
        }
        for (; p < c2; p++) {
            int e = o1 + p;
            unsigned wa = *(const unsigned*)(xbb + (((unsigned)ents[e] << 8) + cb));
            unsigned wb = *(const unsigned*)(xbb + (((unsigned)ents[e + c2] << 8) + cb));
            a1l += blo(wa); a1h += bhi(wa);
            a2l += blo(wb); a2h += bhi(wb);
        }

        // ---- r3 stream: 4-deep x 3 slots ----
        const int o3 = o1 + 2 * c2;
        p = 0;
        for (; p + 4 <= c3; p += 4) {
            unsigned wa[4], wb[4], wc[4];
#pragma unroll
            for (int i = 0; i < 4; i++) {
                int e = o3 + p + i;
                wa[i] = *(const unsigned*)(xbb + (((unsigned)ents[e] << 8) + cb));
                wb[i] = *(const unsigned*)(xbb + (((unsigned)ents[e + c3] << 8) + cb));
                wc[i] = *(const unsigned*)(xbb + (((unsigned)ents[e + 2 * c3] << 8) + cb));
            }
#pragma unroll
            for (int i = 0; i < 4; i++) {
                a3l += blo(wa[i]); a3h += bhi(wa[i]);
                a4l += blo(wb[i]); a4h += bhi(wb[i]);
                a5l += blo(wc[i]); a5h += bhi(wc[i]);
            }
        }
        for (; p < c3; p++) {
            int e = o3 + p;
            unsigned wa = *(const unsigned*)(xbb + (((unsigned)ents[e] << 8) + cb));
            unsigned wb = *(const unsigned*)(xbb + (((unsigned)ents[e + c3] << 8) + cb));
            unsigned wc = *(const unsigned*)(xbb + (((unsigned)ents[e + 2 * c3] << 8) + cb));
            a3l += blo(wa); a3h += bhi(wa);
            a4l += blo(wb); a4h += bhi(wb);
            a5l += blo(wc); a5h += bhi(wc);
        }

        const float i1 = c1 ? 1.0f / (float)c1 : 0.0f;
        const float i2 = c2 ? 1.0f / (float)c2 : 0.0f;
        const float i3 = c3 ? 1.0f / (float)c3 : 0.0f;
        char* gd = (char*)G + (size_t)d * 1536 + cb;
        __builtin_nontemporal_store(pk(a0l * i1, a0h * i1), (unsigned*)gd);
        __builtin_nontemporal_store(pk(a1l * i2, a1h * i2), (unsigned*)(gd + 256));
        __builtin_nontemporal_store(pk(a2l * i2, a2h * i2), (unsigned*)(gd + 512));
        __builtin_nontemporal_store(pk(a3l * i3, a3h * i3), (unsigned*)(gd + 768));
        __builtin_nontemporal_store(pk(a4l * i3, a4h * i3), (unsigned*)(gd + 1024));
        __builtin_nontemporal_store(pk(a5l * i3, a5h * i3), (unsigned*)(gd + 1280));
    }
}

// ---------------- K3: out = [G | xb] @ Acat + Cb  (K = 896) ----------------
// Unchanged from round 5. MFMA C layout: col=lane&15, row=quad*4+reg.

__global__ __launch_bounds__(256) void gemm_out(
    const u16* __restrict__ G, const u16* __restrict__ xb,
    const u16* __restrict__ AT, const float* __restrict__ Cb,
    float* __restrict__ out) {
    __shared__ __align__(16) float smemf[64 * 132];  // 33792 B; first 20480 B aliased as Xs
    typedef u16 XsT[64][40];
    XsT* Xs = reinterpret_cast<XsT*>(smemf);

    const int t = threadIdx.x;
    const int d0 = blockIdx.x * 64;
    const int lane = t & 63, wv = t >> 6;
    const int nbase = wv * 32, quad = lane >> 4, lrow = lane & 15;

    f32x4 acc[4][2];
#pragma unroll
    for (int mi = 0; mi < 4; mi++)
#pragma unroll
        for (int ni = 0; ni < 2; ni++) acc[mi][ni] = (f32x4)(0.0f);

    for (int s = 0; s < 7; s++) {
        // stage 64 rows x 128 k of slot s (16B per thread-iter, nt loads)
#pragma unroll
        for (int i = 0; i < 4; i++) {
            int f = i * 256 + t;
            int row = f >> 4, k8 = f & 15;
            long rs = (d0 + row < N_NODES) ? d0 + row : N_NODES - 1;
            const u16* src = (s < 6) ? (G + rs * 768 + s * 128 + k8 * 8)
                                     : (xb + rs * 128 + k8 * 8);
            u32x4 v = __builtin_nontemporal_load((const u32x4*)src);
            *(u32x4*)&Xs[k8 >> 2][row][(k8 & 3) * 8] = v;
        }
        __syncthreads();
        const u16* B = AT + s * 16384;
        s16x8 bfrag[2][4];
#pragma unroll
        for (int ni = 0; ni < 2; ni++)
#pragma unroll
            for (int c = 0; c < 4; c++)
                bfrag[ni][c] = *(const s16x8*)(B + (nbase + ni * 16 + lrow) * 128 +
                                               c * 32 + quad * 8);
        s16x8 afrag[4][4];
#pragma unroll
        for (int mi = 0; mi < 4; mi++)
#pragma unroll
            for (int c = 0; c < 4; c++)
                afrag[mi][c] = *(const s16x8*)&Xs[c][mi * 16 + lrow][quad * 8];
#pragma unroll
        for (int c = 0; c < 4; c++)
#pragma unroll
            for (int mi = 0; mi < 4; mi++)
#pragma unroll
                for (int ni = 0; ni < 2; ni++)
                    acc[mi][ni] = __builtin_amdgcn_mfma_f32_16x16x32_bf16(
                        afrag[mi][c], bfrag[ni][c], acc[mi][ni], 0, 0, 0);
        __syncthreads();  // Xs reads done before next slot overwrites
    }

    // epilogue: LDS bounce, +Cb, coalesced nt float4 stores
#pragma unroll
    for (int mi = 0; mi < 4; mi++)
#pragma unroll
        for (int ni = 0; ni < 2; ni++)
#pragma unroll
            for (int reg = 0; reg < 4; reg++) {
                int row = mi * 16 + quad * 4 + reg;
                int colq = nbase + ni * 16 + lrow;
                smemf[row * 132 + colq] = acc[mi][ni][reg];
            }
    __syncthreads();
#pragma unroll
    for (int i = 0; i < 8; i++) {
        int f = i * 256 + t;
        int row = f >> 5;
        int colq = (f & 31) * 4;
        if (d0 + row < N_NODES) {
            f32x4 v = *(const f32x4*)&smemf[row * 132 + colq];
            f32x4 b = *(const f32x4*)&Cb[colq];
            v += b;
            __builtin_nontemporal_store(v, (f32x4*)&out[(long)(d0 + row) * 128 + colq]);
        }
    }
}

// ---------------- launcher ----------------

extern "C" void kernel_launch(void* const* d_in, const int* in_sizes, int n_in,
                              void* d_out, int out_size, void* d_ws, size_t ws_size,
                              hipStream_t stream) {
    const float* x  = (const float*)d_in[0];
    const float* A1 = (const float*)d_in[1];
    const float* A2 = (const float*)d_in[2];
    const float* A3 = (const float*)d_in[3];
    const float* Cw = (const float*)d_in[4];
    const float* Cb = (const float*)d_in[5];
    const int* e1 = (const int*)d_in[6];
    const int* e2 = (const int*)d_in[7];
    const int* e3 = (const int*)d_in[8];
    float* out = (float*)d_out;

    int* ws = (int*)d_ws;
    int* deg    = ws;
    int* offs   = ws + 300000;
    int* cursor = ws + 400001;
    int* flags  = ws + 700001;
    int* ents   = (int*)((char*)d_ws + ENTS_OFF);
    u16* ATb    = (u16*)((char*)d_ws + AT_OFF);
    u16* xb     = (u16*)((char*)d_ws + XB_OFF);
    u16* G      = (u16*)((char*)d_ws + G_OFF);

    int ne1 = in_sizes[6] / 2;        // 400000
    int ne2 = in_sizes[7] / (2 * 2);  // 300000
    int ne3 = in_sizes[8] / (2 * 3);  // 200000

    void* args[] = {&x, &A1, &A2, &A3, &Cw, &e1, &e2, &e3,
                    &ne1, &ne2, &ne3, &ATb, &xb, &deg, &offs, &cursor, &flags, &ents};
    hipLaunchCooperativeKernel((const void*)pre_all, dim3(1024), dim3(256),
                               args, 0, stream);
    agg_all<<<2048, 256, 0, stream>>>(xb, ents, offs, deg, G);
    gemm_out<<<(N_NODES + 63) / 64, 256, 0, stream>>>(G, xb, ATb, Cb, out);
}

// Round 7
// 356.683 us; speedup vs baseline: 1.7689x; 1.7689x over previous
//
#include <hip/hip_runtime.h>

#define N_NODES 100000
#define D 128

typedef unsigned short u16;
typedef short s16x8 __attribute__((ext_vector_type(8)));
typedef float f32x4 __attribute__((ext_vector_type(4)));
typedef unsigned u32x4 __attribute__((ext_vector_type(4)));

// ---------------- ws layout ----------------
// ints (4B):
//   deg    @ 0        (300000)   per-type in-degree [type*100000 + d]
//   flags  @ 300000   (128)      lookback-scan state (adjacent to deg: one memset)
//   offs   @ 300128   (100001)   unified entry-list exclusive scan (+sentinel)
//   cursor @ 400129   (300000)   per-(type,dest) segment cursors
// int  ents @ byte 2804224  (1,600,000 x 4B = 6.4 MB)  src node index only
// u16  ATb  @ byte 9204224  (7 x 16384 = 229 KB)  transposed bf16 weights [slot][n][k]
// u16  xb   @ byte 9433600  (100000 x 128 = 25.6 MB) compact bf16 x
// u16  G    @ byte 35033600 (100000 x 6 x 128 = 153.6 MB) aggregated slots (nt streamed)

#define ENTS_OFF 2804224L
#define AT_OFF   9204224L
#define XB_OFF   9433600L
#define G_OFF    35033600L

__device__ __forceinline__ u16 f2b(float f) {
    union { float f; unsigned u; } v; v.f = f;
    unsigned r = (v.u + 0x7FFFu + ((v.u >> 16) & 1u)) >> 16;
    return (u16)r;
}
__device__ __forceinline__ unsigned pk(float lo, float hi) {
    return (unsigned)f2b(lo) | ((unsigned)f2b(hi) << 16);
}
__device__ __forceinline__ float blo(unsigned w) { return __uint_as_float(w << 16); }
__device__ __forceinline__ float bhi(unsigned w) { return __uint_as_float(w & 0xFFFF0000u); }

// ---------------- K1: per-type in-degree only ----------------

__global__ __launch_bounds__(256) void deg_all(
    const int* __restrict__ e1, const int* __restrict__ e2, const int* __restrict__ e3,
    int ne1, int ne2, int ne3, int* __restrict__ deg) {
    int g = blockIdx.x * 256 + threadIdx.x;
    if (g < ne1) {
        atomicAdd(&deg[e1[ne1 + g]], 1);
    } else if (g < ne1 + ne2) {
        int e = g - ne1;
        atomicAdd(&deg[N_NODES + e2[ne2 * 2 + e * 2]], 1);
    } else if (g < ne1 + ne2 + ne3) {
        int e = g - ne1 - ne2;
        atomicAdd(&deg[2 * N_NODES + e3[ne3 * 3 + e * 3]], 1);
    }
}

// ---------------- K2: lookback scan (blocks 0..97) + ATb convert (blocks 98..545) ----
// Lookback chain only spans blocks 0..97, which dispatch first -> co-resident, safe.

__global__ __launch_bounds__(256) void scan_atb(
    const int* __restrict__ deg, int* __restrict__ offs, int* __restrict__ cursor,
    int* __restrict__ flags,
    const float* __restrict__ A1, const float* __restrict__ A2,
    const float* __restrict__ A3, const float* __restrict__ Cw,
    u16* __restrict__ ATb, int n, int nb) {
    const int t = threadIdx.x, bid = blockIdx.x;
    if (bid >= nb) {
        // weight transpose/convert: 448 blocks, slot m = (bid-nb)>>6
        int mb = bid - nb;
        int m = mb >> 6;
        int idx = (mb & 63) * 256 + t;  // 0..16383
        int nn = idx >> 7, kk = idx & 127;
        const float* src; int srow;
        if (m == 0)      { src = A1; srow = kk; }
        else if (m < 3)  { src = A2; srow = (m - 1) * 128 + kk; }
        else if (m < 6)  { src = A3; srow = (m - 3) * 128 + kk; }
        else             { src = Cw; srow = kk; }
        ATb[m * 16384 + nn * 128 + kk] = f2b(src[(long)srow * 128 + nn]);
        return;
    }
    __shared__ int s[256];
    __shared__ int bprefix;
    int base = bid * 1024 + t * 4;
    int d1[4], d2[4], v[4], p[4];
#pragma unroll
    for (int r = 0; r < 4; r++) {
        int idx = base + r;
        if (idx < n) {
            d1[r] = deg[idx];
            d2[r] = deg[N_NODES + idx];
            int d3 = deg[2 * N_NODES + idx];
            v[r] = d1[r] + 2 * d2[r] + 3 * d3;
        } else { d1[r] = 0; d2[r] = 0; v[r] = 0; }
    }
    p[0] = 0; p[1] = v[0]; p[2] = v[0] + v[1]; p[3] = v[0] + v[1] + v[2];
    int tsum = p[3] + v[3];
    s[t] = tsum;
    for (int off = 1; off < 256; off <<= 1) {
        __syncthreads();
        int x = (t >= off) ? s[t - off] : 0;
        __syncthreads();
        s[t] += x;
    }
    __syncthreads();
    int total = s[255];
    if (t == 0) {
        int run = 0;
        if (bid == 0) {
            atomicExch(&flags[0], (total << 2) | 2);
        } else {
            atomicExch(&flags[bid], (total << 2) | 1);
            int j = bid - 1;
            while (true) {
                int f = atomicAdd(&flags[j], 0);
                int st = f & 3;
                if (st == 0) continue;
                run += (f >> 2);
                if (st == 2) break;
                j--;
            }
            atomicExch(&flags[bid], ((run + total) << 2) | 2);
        }
        bprefix = run;
        if (bid == nb - 1) offs[n] = run + total;
    }
    __syncthreads();
    int texcl = s[t] - tsum + bprefix;
#pragma unroll
    for (int r = 0; r < 4; r++) {
        int idx = base + r;
        if (idx < n) {
            int val = texcl + p[r];
            offs[idx] = val;
            cursor[idx] = val;                                    // r1 segment
            cursor[N_NODES + idx] = val + d1[r];                  // r2 slot-1 segment
            cursor[2 * N_NODES + idx] = val + d1[r] + 2 * d2[r];  // r3 slot-3 segment
        }
    }
}

// ---------------- K3: scatter (latency-bound) || x->bf16 convert (BW-bound) ----------
// blocks [0,6250): x->xb streaming convert; blocks [6250,..): slot-segmented scatter.
// dest range layout: [c1 slot0][c2 slot1][c2 slot2][c3 slot3][c3 slot4][c3 slot5]

__global__ __launch_bounds__(256) void scatter_xconv(
    const float* __restrict__ x, u16* __restrict__ xb,
    const int* __restrict__ e1, const int* __restrict__ e2, const int* __restrict__ e3,
    int ne1, int ne2, int ne3, const int* __restrict__ deg,
    int* __restrict__ cursor, int* __restrict__ ents) {
    int b = blockIdx.x, t = threadIdx.x;
    if (b < 6250) {
        int f = b * 256 + t;                  // 0..1,599,999 exact
        int node = f >> 4, j = f & 15;
        const f32x4* xr = (const f32x4*)(x + (long)node * 128 + j * 8);
        f32x4 v0 = __builtin_nontemporal_load(xr);
        f32x4 v1 = __builtin_nontemporal_load(xr + 1);
        u32x4 o;
        o.x = pk(v0.x, v0.y); o.y = pk(v0.z, v0.w);
        o.z = pk(v1.x, v1.y); o.w = pk(v1.z, v1.w);
        *(u32x4*)(xb + (long)node * 128 + j * 8) = o;
        return;
    }
    int g = (b - 6250) * 256 + t;
    if (g < ne1) {
        int dest = e1[ne1 + g];
        int pos = atomicAdd(&cursor[dest], 1);
        ents[pos] = e1[g];
    } else if (g < ne1 + ne2) {
        int e = g - ne1;
        int dest = e2[ne2 * 2 + e * 2];
        int c2 = deg[N_NODES + dest];
        int pos = atomicAdd(&cursor[N_NODES + dest], 1);
        ents[pos]      = e2[e * 2];
        ents[pos + c2] = e2[e * 2 + 1];
    } else if (g < ne1 + ne2 + ne3) {
        int e = g - ne1 - ne2;
        int dest = e3[ne3 * 3 + e * 3];
        int c3 = deg[2 * N_NODES + dest];
        int pos = atomicAdd(&cursor[2 * N_NODES + dest], 1);
        ents[pos]          = e3[e * 3];
        ents[pos + c3]     = e3[e * 3 + 1];
        ents[pos + 2 * c3] = e3[e * 3 + 2];
    }
}

// ---------------- K4: aggregate — G[d][s] = (1/c_t) * sum xb[src] ----------------
// Unchanged from round 5 (81 us; fetch at compulsory cross-XCD floor).

__global__ __launch_bounds__(256) void agg_all(
    const u16* __restrict__ xb, const int* __restrict__ ents,
    const int* __restrict__ offs, const int* __restrict__ deg,
    u16* __restrict__ G) {
    const int lane = threadIdx.x & 63;
    const int wv = __builtin_amdgcn_readfirstlane(threadIdx.x >> 6);
    int wid = blockIdx.x * 4 + wv;
    const int nw = gridDim.x * 4;
    const unsigned cb = (unsigned)lane * 4u;  // lane's byte offset within a 256B row
    const char* xbb = (const char*)xb;

    for (int d = wid; d < N_NODES; d += nw) {
        const int lo = offs[d];
        const int c1 = deg[d], c2 = deg[N_NODES + d], c3 = deg[2 * N_NODES + d];
        float a0l = 0, a0h = 0, a1l = 0, a1h = 0, a2l = 0, a2h = 0;
        float a3l = 0, a3h = 0, a4l = 0, a4h = 0, a5l = 0, a5h = 0;

        // ---- r1 stream: 8-deep unmasked batches + tail ----
        int p = 0;
        for (; p + 8 <= c1; p += 8) {
            unsigned w[8];
#pragma unroll
            for (int i = 0; i < 8; i++)
                w[i] = *(const unsigned*)(xbb + (((unsigned)ents[lo + p + i] << 8) + cb));
#pragma unroll
            for (int i = 0; i < 8; i++) { a0l += blo(w[i]); a0h += bhi(w[i]); }
        }
        for (; p < c1; p++) {
            unsigned w = *(const unsigned*)(xbb + (((unsigned)ents[lo + p] << 8) + cb));
            a0l += blo(w); a0h += bhi(w);
        }

        // ---- r2 stream: 4-deep x 2 slots ----
        const int o1 = lo + c1;
        p = 0;
        for (; p + 4 <= c2; p += 4) {
            unsigned wa[4], wb[4];
#pragma unroll
            for (int i = 0; i < 4; i++) {
                int e = o1 + p + i;
                wa[i] = *(const unsigned*)(xbb + (((unsigned)ents[e] << 8) + cb));
                wb[i] = *(const unsigned*)(xbb + (((unsigned)ents[e + c2] << 8) + cb));
            }
#pragma unroll
            for (int i = 0; i < 4; i++) {
                a1l += blo(wa[i]); a1h += bhi(wa[i]);
                a2l += blo(wb[i]); a2h += bhi(wb[i]);
            }
        }
        for (; p < c2; p++) {
            int e = o1 + p;
            unsigned wa = *(const unsigned*)(xbb + (((unsigned)ents[e] << 8) + cb));
            unsigned wb = *(const unsigned*)(xbb + (((unsigned)ents[e + c2] << 8) + cb));
            a1l += blo(wa); a1h += bhi(wa);
            a2l += blo(wb); a2h += bhi(wb);
        }

        // ---- r3 stream: 4-deep x 3 slots ----
        const int o3 = o1 + 2 * c2;
        p = 0;
        for (; p + 4 <= c3; p += 4) {
            unsigned wa[4], wb[4], wc[4];
#pragma unroll
            for (int i = 0; i < 4; i++) {
                int e = o3 + p + i;
                wa[i] = *(const unsigned*)(xbb + (((unsigned)ents[e] << 8) + cb));
                wb[i] = *(const unsigned*)(xbb + (((unsigned)ents[e + c3] << 8) + cb));
                wc[i] = *(const unsigned*)(xbb + (((unsigned)ents[e + 2 * c3] << 8) + cb));
            }
#pragma unroll
            for (int i = 0; i < 4; i++) {
                a3l += blo(wa[i]); a3h += bhi(wa[i]);
                a4l += blo(wb[i]); a4h += bhi(wb[i]);
                a5l += blo(wc[i]); a5h += bhi(wc[i]);
            }
        }
        for (; p < c3; p++) {
            int e = o3 + p;
            unsigned wa = *(const unsigned*)(xbb + (((unsigned)ents[e] << 8) + cb));
            unsigned wb = *(const unsigned*)(xbb + (((unsigned)ents[e + c3] << 8) + cb));
            unsigned wc = *(const unsigned*)(xbb + (((unsigned)ents[e + 2 * c3] << 8) + cb));
            a3l += blo(wa); a3h += bhi(wa);
            a4l += blo(wb); a4h += bhi(wb);
            a5l += blo(wc); a5h += bhi(wc);
        }

        const float i1 = c1 ? 1.0f / (float)c1 : 0.0f;
        const float i2 = c2 ? 1.0f / (float)c2 : 0.0f;
        const float i3 = c3 ? 1.0f / (float)c3 : 0.0f;
        char* gd = (char*)G + (size_t)d * 1536 + cb;
        __builtin_nontemporal_store(pk(a0l * i1, a0h * i1), (unsigned*)gd);
        __builtin_nontemporal_store(pk(a1l * i2, a1h * i2), (unsigned*)(gd + 256));
        __builtin_nontemporal_store(pk(a2l * i2, a2h * i2), (unsigned*)(gd + 512));
        __builtin_nontemporal_store(pk(a3l * i3, a3h * i3), (unsigned*)(gd + 768));
        __builtin_nontemporal_store(pk(a4l * i3, a4h * i3), (unsigned*)(gd + 1024));
        __builtin_nontemporal_store(pk(a5l * i3, a5h * i3), (unsigned*)(gd + 1280));
    }
}

// ---------------- K5: out = [G | xb] @ Acat + Cb  (K = 896, double-buffered) --------
// T14 async-stage: issue slot s+1 global->reg loads BEFORE slot-s MFMA (latency hides
// under MFMA), write regs->other LDS buffer after, ONE barrier per slot (was two).
// Ping-pong: MFMA slot s reads Xs[s&1]; slot s+1 written to Xs[(s+1)&1] (safe: that
// buffer's last readers finished before the end-of-iteration-(s-1) barrier).
// MFMA C layout: col=lane&15, row=quad*4+reg (validated rounds 0-5).

__global__ __launch_bounds__(256) void gemm_out(
    const u16* __restrict__ G, const u16* __restrict__ xb,
    const u16* __restrict__ AT, const float* __restrict__ Cb,
    float* __restrict__ out) {
    __shared__ __align__(16) u16 Xs[2][4][64][40];  // 40,960 B; epilogue aliases as f32

    const int t = threadIdx.x;
    const int d0 = blockIdx.x * 64;
    const int lane = t & 63, wv = t >> 6;
    const int nbase = wv * 32, quad = lane >> 4, lrow = lane & 15;

    f32x4 acc[4][2];
#pragma unroll
    for (int mi = 0; mi < 4; mi++)
#pragma unroll
        for (int ni = 0; ni < 2; ni++) acc[mi][ni] = (f32x4)(0.0f);

    u32x4 stg[4];
    // prologue: slot 0 -> regs -> Xs[0]
#pragma unroll
    for (int i = 0; i < 4; i++) {
        int f = i * 256 + t;
        int row = f >> 4, k8 = f & 15;
        long rs = (d0 + row < N_NODES) ? d0 + row : N_NODES - 1;
        stg[i] = __builtin_nontemporal_load((const u32x4*)(G + rs * 768 + k8 * 8));
    }
#pragma unroll
    for (int i = 0; i < 4; i++) {
        int f = i * 256 + t;
        int row = f >> 4, k8 = f & 15;
        *(u32x4*)&Xs[0][k8 >> 2][row][(k8 & 3) * 8] = stg[i];
    }
    __syncthreads();

    for (int s = 0; s < 7; s++) {
        // issue next slot's global loads first (hide under MFMA)
        if (s < 6) {
#pragma unroll
            for (int i = 0; i < 4; i++) {
                int f = i * 256 + t;
                int row = f >> 4, k8 = f & 15;
                long rs = (d0 + row < N_NODES) ? d0 + row : N_NODES - 1;
                const u16* src = (s + 1 < 6) ? (G + rs * 768 + (s + 1) * 128 + k8 * 8)
                                             : (xb + rs * 128 + k8 * 8);
                stg[i] = __builtin_nontemporal_load((const u32x4*)src);
            }
        }
        const u16* B = AT + s * 16384;
        s16x8 bfrag[2][4];
#pragma unroll
        for (int ni = 0; ni < 2; ni++)
#pragma unroll
            for (int c = 0; c < 4; c++)
                bfrag[ni][c] = *(const s16x8*)(B + (nbase + ni * 16 + lrow) * 128 +
                                               c * 32 + quad * 8);
        const int cur = s & 1;
#pragma unroll
        for (int c = 0; c < 4; c++) {
            s16x8 a[4];
#pragma unroll
            for (int mi = 0; mi < 4; mi++)
                a[mi] = *(const s16x8*)&Xs[cur][c][mi * 16 + lrow][quad * 8];
#pragma unroll
            for (int mi = 0; mi < 4; mi++)
#pragma unroll
                for (int ni = 0; ni < 2; ni++)
                    acc[mi][ni] = __builtin_amdgcn_mfma_f32_16x16x32_bf16(
                        a[mi], bfrag[ni][c], acc[mi][ni], 0, 0, 0);
        }
        if (s < 6) {
            // write staged slot s+1 into the other buffer (no barrier needed before:
            // its previous readers completed before the last barrier)
#pragma unroll
            for (int i = 0; i < 4; i++) {
                int f = i * 256 + t;
                int row = f >> 4, k8 = f & 15;
                *(u32x4*)&Xs[cur ^ 1][k8 >> 2][row][(k8 & 3) * 8] = stg[i];
            }
        }
        __syncthreads();
    }

    // epilogue: LDS bounce (aliases Xs), +Cb, coalesced nt float4 stores
    float* smf = (float*)&Xs[0][0][0][0];
#pragma unroll
    for (int mi = 0; mi < 4; mi++)
#pragma unroll
        for (int ni = 0; ni < 2; ni++)
#pragma unroll
            for (int reg = 0; reg < 4; reg++) {
                int row = mi * 16 + quad * 4 + reg;
                int colq = nbase + ni * 16 + lrow;
                smf[row * 132 + colq] = acc[mi][ni][reg];
            }
    __syncthreads();
#pragma unroll
    for (int i = 0; i < 8; i++) {
        int f = i * 256 + t;
        int row = f >> 5;
        int colq = (f & 31) * 4;
        if (d0 + row < N_NODES) {
            f32x4 v = *(const f32x4*)&smf[row * 132 + colq];
            f32x4 b = *(const f32x4*)&Cb[colq];
            v += b;
            __builtin_nontemporal_store(v, (f32x4*)&out[(long)(d0 + row) * 128 + colq]);
        }
    }
}

// ---------------- launcher ----------------

extern "C" void kernel_launch(void* const* d_in, const int* in_sizes, int n_in,
                              void* d_out, int out_size, void* d_ws, size_t ws_size,
                              hipStream_t stream) {
    const float* x  = (const float*)d_in[0];
    const float* A1 = (const float*)d_in[1];
    const float* A2 = (const float*)d_in[2];
    const float* A3 = (const float*)d_in[3];
    const float* Cw = (const float*)d_in[4];
    const float* Cb = (const float*)d_in[5];
    const int* e1 = (const int*)d_in[6];
    const int* e2 = (const int*)d_in[7];
    const int* e3 = (const int*)d_in[8];
    float* out = (float*)d_out;

    int* ws = (int*)d_ws;
    int* deg    = ws;
    int* flags  = ws + 300000;
    int* offs   = ws + 300128;
    int* cursor = ws + 400129;
    int* ents   = (int*)((char*)d_ws + ENTS_OFF);
    u16* ATb    = (u16*)((char*)d_ws + AT_OFF);
    u16* xb     = (u16*)((char*)d_ws + XB_OFF);
    u16* G      = (u16*)((char*)d_ws + G_OFF);

    const int NE1 = in_sizes[6] / 2;        // 400000
    const int NE2 = in_sizes[7] / (2 * 2);  // 300000
    const int NE3 = in_sizes[8] / (2 * 3);  // 200000
    const int NET = NE1 + NE2 + NE3;        // 900000
    const int n = N_NODES;
    const int NB = (n + 1023) / 1024;       // 98

    // zero deg + flags in one DMA memset (graph-capture-safe; harness uses memsets)
    hipMemsetAsync(deg, 0, (300000 + 128) * sizeof(int), stream);
    deg_all<<<(NET + 255) / 256, 256, 0, stream>>>(e1, e2, e3, NE1, NE2, NE3, deg);
    scan_atb<<<NB + 448, 256, 0, stream>>>(deg, offs, cursor, flags,
                                           A1, A2, A3, Cw, ATb, n, NB);
    scatter_xconv<<<6250 + (NET + 255) / 256, 256, 0, stream>>>(
        x, xb, e1, e2, e3, NE1, NE2, NE3, deg, cursor, ents);
    agg_all<<<2048, 256, 0, stream>>>(xb, ents, offs, deg, G);
    gemm_out<<<(N_NODES + 63) / 64, 256, 0, stream>>>(G, xb, ATb, Cb, out);
}